// Round 1
// baseline (771.957 us; speedup 1.0000x reference)
//
#include <hip/hip_runtime.h>
#include <hip/hip_bf16.h>

#define T_TOK 4096
#define D_MODEL 1024
#define I_DIM 2048
#define E_EXP 16

typedef __bf16 bf16x8 __attribute__((ext_vector_type(8)));
typedef float f32x4 __attribute__((ext_vector_type(4)));
typedef unsigned int u32x4 __attribute__((ext_vector_type(4)));

// XOR swizzle: [row][4 x 16B chunks] per 64B row; chunk ^= (row>>1)&3 keeps
// ds_read_b128 column reads at <=2-way bank conflict (free per m136).
__device__ __forceinline__ int swz(int row, int chunk) {
    return row * 64 + (((chunk ^ ((row >> 1) & 3)) & 3) << 4);
}

__device__ __forceinline__ bf16x8 pack8(f32x4 a, f32x4 b) {
    bf16x8 r;
    r[0] = (__bf16)a[0]; r[1] = (__bf16)a[1]; r[2] = (__bf16)a[2]; r[3] = (__bf16)a[3];
    r[4] = (__bf16)b[0]; r[5] = (__bf16)b[1]; r[6] = (__bf16)b[2]; r[7] = (__bf16)b[3];
    return r;
}

// ---------------- Router: logits (fp64 accum), top-4, softmax-over-top4,
// atomic append to per-expert token lists. One wave per token. ----------------
__global__ __launch_bounds__(256) void router_kernel(
    const float* __restrict__ x, const float* __restrict__ rw,
    int* __restrict__ counts, int* __restrict__ tok_list, float* __restrict__ gate_list)
{
    const int wid = threadIdx.x >> 6, lane = threadIdx.x & 63;
    const int t = blockIdx.x * 4 + wid;
    const int e = lane & 15, part = lane >> 4;

    const float* xr = x + (size_t)t * D_MODEL + part * 256;
    const float* wr = rw + (size_t)e * D_MODEL + part * 256;
    double acc = 0.0;
    #pragma unroll 4
    for (int i = 0; i < 256; i += 4) {
        f32x4 xv = *(const f32x4*)(xr + i);
        f32x4 wv = *(const f32x4*)(wr + i);
        acc += (double)xv[0] * wv[0] + (double)xv[1] * wv[1]
             + (double)xv[2] * wv[2] + (double)xv[3] * wv[3];
    }
    acc += __shfl_xor(acc, 16, 64);
    acc += __shfl_xor(acc, 32, 64);

    __shared__ float logits[4][16];
    if (lane < 16) logits[wid][lane] = (float)acc;
    __syncthreads();

    if (lane == 0) {
        float l[16];
        #pragma unroll
        for (int i = 0; i < 16; i++) l[i] = logits[wid][i];
        int idx[4]; float val[4];
        unsigned taken = 0;
        for (int k = 0; k < 4; k++) {
            int best = 0; float bv = -1e30f;
            for (int i = 0; i < 16; i++)
                if (!((taken >> i) & 1) && l[i] > bv) { bv = l[i]; best = i; }
            idx[k] = best; val[k] = bv; taken |= (1u << best);
        }
        float m = val[0];
        float w[4], s = 0.f;
        for (int k = 0; k < 4; k++) { w[k] = __expf(val[k] - m); s += w[k]; }
        for (int k = 0; k < 4; k++) {
            int ee = idx[k];
            int slot = atomicAdd(&counts[ee], 1);
            tok_list[ee * T_TOK + slot] = t;
            gate_list[ee * T_TOK + slot] = w[k] / s;
        }
    }
}

__global__ void prefix_kernel(const int* __restrict__ counts, int* __restrict__ prefix) {
    if (threadIdx.x == 0) {
        int acc = 0;
        for (int e = 0; e < E_EXP; e++) { prefix[e] = acc; acc += (counts[e] + 127) & ~127; }
        prefix[E_EXP] = acc;
    }
}

// ---------------- GEMM1 + SwiGLU: act[row, n] = silu(x@w1^T) * (x@v1^T), bf16 out.
// Tile: 128 tokens x 64 act-cols (both halves computed), BK=32, 4 waves. ----------
__global__ __launch_bounds__(256) void gemm1_kernel(
    const float* __restrict__ x, const float* __restrict__ wsw,
    const int* __restrict__ counts, const int* __restrict__ prefix,
    const int* __restrict__ tok_list, __bf16* __restrict__ act)
{
    const int e = blockIdx.z;
    const int count = counts[e];
    const int tileM = blockIdx.y;
    if (tileM * 128 >= count) return;
    const int tileN = blockIdx.x;

    const int tid = threadIdx.x;
    const int lane = tid & 63, wid = tid >> 6;
    const int l15 = lane & 15, ch = lane >> 4;

    __shared__ char smem[32768];
    char* As = smem;           // [2][8192] : 128 rows x 32 k bf16
    char* Bs = smem + 16384;   // [2][8192] : 128 rows x 32 k bf16

    const int trow = tid >> 1;
    const int tk16 = (tid & 1) << 4;
    const int c0 = (tid & 1) << 1;

    int r = tileM * 128 + trow;
    int rr = (r < count) ? r : (count - 1);
    const int token = tok_list[e * T_TOK + rr];
    const float* aptr = x + (size_t)token * D_MODEL + tk16;
    const int gcol = (trow < 64) ? (tileN * 64 + trow) : (I_DIM + tileN * 64 + trow - 64);
    const float* bptr = wsw + ((size_t)e * (2 * I_DIM) + gcol) * D_MODEL + tk16;

    f32x4 acc1[2][4], acc2[2][4];
    const f32x4 z = {0.f, 0.f, 0.f, 0.f};
    #pragma unroll
    for (int m = 0; m < 2; m++)
        #pragma unroll
        for (int n = 0; n < 4; n++) { acc1[m][n] = z; acc2[m][n] = z; }

    { // prologue: stage k0 = 0 into buf 0
        f32x4 a0 = *(const f32x4*)(aptr + 0),  a1 = *(const f32x4*)(aptr + 4);
        f32x4 a2 = *(const f32x4*)(aptr + 8),  a3 = *(const f32x4*)(aptr + 12);
        f32x4 b0 = *(const f32x4*)(bptr + 0),  b1 = *(const f32x4*)(bptr + 4);
        f32x4 b2 = *(const f32x4*)(bptr + 8),  b3 = *(const f32x4*)(bptr + 12);
        *(bf16x8*)(As + swz(trow, c0))     = pack8(a0, a1);
        *(bf16x8*)(As + swz(trow, c0 + 1)) = pack8(a2, a3);
        *(bf16x8*)(Bs + swz(trow, c0))     = pack8(b0, b1);
        *(bf16x8*)(Bs + swz(trow, c0 + 1)) = pack8(b2, b3);
    }
    __syncthreads();

    const int wrow = wid * 32 + l15;
    for (int s = 0; s < 32; ++s) {
        const int cur = s & 1;
        f32x4 av0, av1, av2, av3, bv0, bv1, bv2, bv3;
        const bool pf = (s + 1) < 32;
        if (pf) {
            const int k0 = (s + 1) * 32;
            av0 = *(const f32x4*)(aptr + k0);      av1 = *(const f32x4*)(aptr + k0 + 4);
            av2 = *(const f32x4*)(aptr + k0 + 8);  av3 = *(const f32x4*)(aptr + k0 + 12);
            bv0 = *(const f32x4*)(bptr + k0);      bv1 = *(const f32x4*)(bptr + k0 + 4);
            bv2 = *(const f32x4*)(bptr + k0 + 8);  bv3 = *(const f32x4*)(bptr + k0 + 12);
        }
        char* A = As + cur * 8192;
        char* B = Bs + cur * 8192;
        bf16x8 af0 = *(bf16x8*)(A + swz(wrow, ch));
        bf16x8 af1 = *(bf16x8*)(A + swz(wrow + 16, ch));
        bf16x8 b1f[4], b2f[4];
        #pragma unroll
        for (int n = 0; n < 4; n++) {
            b1f[n] = *(bf16x8*)(B + swz(n * 16 + l15, ch));
            b2f[n] = *(bf16x8*)(B + swz(64 + n * 16 + l15, ch));
        }
        #pragma unroll
        for (int n = 0; n < 4; n++) {
            acc1[0][n] = __builtin_amdgcn_mfma_f32_16x16x32_bf16(af0, b1f[n], acc1[0][n], 0, 0, 0);
            acc1[1][n] = __builtin_amdgcn_mfma_f32_16x16x32_bf16(af1, b1f[n], acc1[1][n], 0, 0, 0);
            acc2[0][n] = __builtin_amdgcn_mfma_f32_16x16x32_bf16(af0, b2f[n], acc2[0][n], 0, 0, 0);
            acc2[1][n] = __builtin_amdgcn_mfma_f32_16x16x32_bf16(af1, b2f[n], acc2[1][n], 0, 0, 0);
        }
        if (pf) {
            char* An = As + (cur ^ 1) * 8192;
            char* Bn = Bs + (cur ^ 1) * 8192;
            *(bf16x8*)(An + swz(trow, c0))     = pack8(av0, av1);
            *(bf16x8*)(An + swz(trow, c0 + 1)) = pack8(av2, av3);
            *(bf16x8*)(Bn + swz(trow, c0))     = pack8(bv0, bv1);
            *(bf16x8*)(Bn + swz(trow, c0 + 1)) = pack8(bv2, bv3);
        }
        __syncthreads();
    }

    const int abase = prefix[e];
    #pragma unroll
    for (int m = 0; m < 2; m++) {
        #pragma unroll
        for (int j = 0; j < 4; j++) {
            const int rrow = tileM * 128 + wid * 32 + m * 16 + ch * 4 + j;
            if (rrow < count) {
                __bf16* arow = act + (size_t)(abase + rrow) * I_DIM + tileN * 64 + l15;
                #pragma unroll
                for (int n = 0; n < 4; n++) {
                    const float v1 = acc1[m][n][j], v2 = acc2[m][n][j];
                    const float g = v1 / (1.f + __expf(-v1)) * v2;
                    arow[n * 16] = (__bf16)g;
                }
            }
        }
    }
}

// ---------------- GEMM2: y = act @ w2^T, scatter gate*y into out via atomics.
// Tile: 128 rows x 128 d-cols, K=2048, BK=32, 4 waves. ----------------
__global__ __launch_bounds__(256) void gemm2_kernel(
    const __bf16* __restrict__ act, const float* __restrict__ w2s,
    const int* __restrict__ counts, const int* __restrict__ prefix,
    const int* __restrict__ tok_list, const float* __restrict__ gate_list,
    float* __restrict__ out)
{
    const int e = blockIdx.z;
    const int count = counts[e];
    const int tileM = blockIdx.y;
    if (tileM * 128 >= count) return;
    const int tileN = blockIdx.x;

    const int tid = threadIdx.x;
    const int lane = tid & 63, wid = tid >> 6;
    const int l15 = lane & 15, ch = lane >> 4;

    __shared__ char smem[32768];
    char* As = smem;
    char* Bs = smem + 16384;

    const int trow = tid >> 1;
    const int tk16 = (tid & 1) << 4;
    const int c0 = (tid & 1) << 1;
    const int abase = prefix[e];

    const __bf16* aptr = act + (size_t)(abase + tileM * 128 + trow) * I_DIM + tk16;
    const int dcol = tileN * 128 + trow;
    const float* bptr = w2s + ((size_t)e * D_MODEL + dcol) * I_DIM + tk16;

    f32x4 acc[2][8];
    const f32x4 z = {0.f, 0.f, 0.f, 0.f};
    #pragma unroll
    for (int m = 0; m < 2; m++)
        #pragma unroll
        for (int n = 0; n < 8; n++) acc[m][n] = z;

    { // prologue
        u32x4 a0 = *(const u32x4*)(aptr);
        u32x4 a1 = *(const u32x4*)(aptr + 8);
        f32x4 b0 = *(const f32x4*)(bptr + 0), b1 = *(const f32x4*)(bptr + 4);
        f32x4 b2 = *(const f32x4*)(bptr + 8), b3 = *(const f32x4*)(bptr + 12);
        *(u32x4*)(As + swz(trow, c0))      = a0;
        *(u32x4*)(As + swz(trow, c0 + 1))  = a1;
        *(bf16x8*)(Bs + swz(trow, c0))     = pack8(b0, b1);
        *(bf16x8*)(Bs + swz(trow, c0 + 1)) = pack8(b2, b3);
    }
    __syncthreads();

    const int wrow = wid * 32 + l15;
    for (int s = 0; s < 64; ++s) {
        const int cur = s & 1;
        u32x4 av0, av1;
        f32x4 bv0, bv1, bv2, bv3;
        const bool pf = (s + 1) < 64;
        if (pf) {
            const int k0 = (s + 1) * 32;
            av0 = *(const u32x4*)(aptr + k0);
            av1 = *(const u32x4*)(aptr + k0 + 8);
            bv0 = *(const f32x4*)(bptr + k0);      bv1 = *(const f32x4*)(bptr + k0 + 4);
            bv2 = *(const f32x4*)(bptr + k0 + 8);  bv3 = *(const f32x4*)(bptr + k0 + 12);
        }
        char* A = As + cur * 8192;
        char* B = Bs + cur * 8192;
        bf16x8 af0 = *(bf16x8*)(A + swz(wrow, ch));
        bf16x8 af1 = *(bf16x8*)(A + swz(wrow + 16, ch));
        bf16x8 bf[8];
        #pragma unroll
        for (int n = 0; n < 8; n++)
            bf[n] = *(bf16x8*)(B + swz(n * 16 + l15, ch));
        #pragma unroll
        for (int n = 0; n < 8; n++) {
            acc[0][n] = __builtin_amdgcn_mfma_f32_16x16x32_bf16(af0, bf[n], acc[0][n], 0, 0, 0);
            acc[1][n] = __builtin_amdgcn_mfma_f32_16x16x32_bf16(af1, bf[n], acc[1][n], 0, 0, 0);
        }
        if (pf) {
            char* An = As + (cur ^ 1) * 8192;
            char* Bn = Bs + (cur ^ 1) * 8192;
            *(u32x4*)(An + swz(trow, c0))      = av0;
            *(u32x4*)(An + swz(trow, c0 + 1))  = av1;
            *(bf16x8*)(Bn + swz(trow, c0))     = pack8(bv0, bv1);
            *(bf16x8*)(Bn + swz(trow, c0 + 1)) = pack8(bv2, bv3);
        }
        __syncthreads();
    }

    #pragma unroll
    for (int m = 0; m < 2; m++) {
        #pragma unroll
        for (int j = 0; j < 4; j++) {
            const int rrow = tileM * 128 + wid * 32 + m * 16 + ch * 4 + j;
            if (rrow < count) {
                const int token = tok_list[e * T_TOK + rrow];
                const float gate = gate_list[e * T_TOK + rrow];
                float* orow = out + (size_t)token * D_MODEL + tileN * 128 + l15;
                #pragma unroll
                for (int n = 0; n < 8; n++)
                    atomicAdd(orow + n * 16, gate * acc[m][n][j]);
            }
        }
    }
}

extern "C" void kernel_launch(void* const* d_in, const int* in_sizes, int n_in,
                              void* d_out, int out_size, void* d_ws, size_t ws_size,
                              hipStream_t stream)
{
    const float* x   = (const float*)d_in[0];   // [4096, 1024]
    const float* rw  = (const float*)d_in[1];   // [16, 1024]
    const float* wsw = (const float*)d_in[2];   // [16, 4096, 1024]
    const float* w2s = (const float*)d_in[3];   // [16, 1024, 2048]
    float* out = (float*)d_out;                 // [4096, 1024] fp32

    char* wsb = (char*)d_ws;
    int* counts      = (int*)wsb;                              // 16 ints
    int* prefix      = (int*)(wsb + 128);                      // 17 ints
    int* tok_list    = (int*)(wsb + 1024);                     // 16*4096 ints (256 KB)
    float* gate_list = (float*)(wsb + 1024 + E_EXP * T_TOK * 4); // 256 KB
    __bf16* act      = (__bf16*)(wsb + (1 << 20));             // 18432 x 2048 bf16 (72 MB)

    hipMemsetAsync(counts, 0, E_EXP * sizeof(int), stream);
    hipMemsetAsync(d_out, 0, (size_t)out_size * sizeof(float), stream);

    router_kernel<<<dim3(T_TOK / 4), 256, 0, stream>>>(x, rw, counts, tok_list, gate_list);
    prefix_kernel<<<1, 64, 0, stream>>>(counts, prefix);
    gemm1_kernel<<<dim3(I_DIM / 64, T_TOK / 128, E_EXP), 256, 0, stream>>>(
        x, wsw, counts, prefix, tok_list, act);
    gemm2_kernel<<<dim3(D_MODEL / 128, T_TOK / 128, E_EXP), 256, 0, stream>>>(
        act, w2s, counts, prefix, tok_list, gate_list, out);
}